// Round 8
// baseline (608.693 us; speedup 1.0000x reference)
//
#include <hip/hip_runtime.h>
#include <hip/hip_bf16.h>
#include <stdint.h>

// B=32, T=2048, E=D=A=1024. f32 I/O; x_lens int32.
// Output = [context (32*1024) ; att (32*2048)] f32.
// Pipeline: W_encT bf16 | dec_proj (d-split) |
//   FUSED 256^2 bf16-MFMA energy GEMM: A staged f32->bf16 in-kernel
//   (reg-stage, issue-early/consume-late T14; kills the 384MB cvt pass),
//   B via global_load_lds, 1 barrier + vmcnt(0) per K-tile (race-free),
//   T2 swizzle, T5 setprio, fused v.tanh epilogue |
//   softmax | atomic-free f32 context.

typedef __bf16 bf16;
typedef __bf16 bf16x8 __attribute__((ext_vector_type(8)));
typedef float floatx4 __attribute__((ext_vector_type(4)));

#define T_DIM 2048
#define B_DIM 32
#define K_DIM 1024   // E
#define N_DIM 1024   // A
#define M_DIM (B_DIM * T_DIM)               // 65536

__device__ __forceinline__ void async_copy16(const bf16* g, bf16* l) {
    __builtin_amdgcn_global_load_lds(
        (const __attribute__((address_space(1))) void*)g,
        (__attribute__((address_space(3))) void*)l, 16, 0, 0);
}

__device__ __forceinline__ float fast_tanh(float x) {
    float ax = fabsf(x);
    float e  = __expf(ax + ax);
    float t  = 1.f - 2.f / (e + 1.f);
    return copysignf(t, x);
}

// ------------- W_enc f32 [E,A] -> W_encT bf16 [A,E] -------------------------
__global__ __launch_bounds__(256) void transpose_wenc(
        const float* __restrict__ W, bf16* __restrict__ WT) {
    __shared__ bf16 tile[64][65];
    const int e0 = blockIdx.x * 64, a0 = blockIdx.y * 64;
    const int c = threadIdx.x & 63, r0 = threadIdx.x >> 6;
#pragma unroll
    for (int p = 0; p < 16; ++p) {
        int r = p * 4 + r0;
        tile[r][c] = (bf16)W[(size_t)(e0 + r) * 1024 + a0 + c];
    }
    __syncthreads();
#pragma unroll
    for (int p = 0; p < 16; ++p) {
        int r = p * 4 + r0;
        WT[(size_t)(a0 + r) * 1024 + e0 + c] = tile[c][r];
    }
}

// ------------- dec_proj[b,a] = b_enc[a] + sum_d dec[b,d] W_dec[d,a] ---------
__global__ __launch_bounds__(256) void decproj_kernel(
        const float* __restrict__ dec, const float* __restrict__ Wdec,
        const float* __restrict__ benc, float* __restrict__ dproj) {
    const int bg = blockIdx.x;            // batch group of 8
    const int a0 = blockIdx.y * 64;
    const int al = threadIdx.x & 63;
    const int dq = threadIdx.x >> 6;      // d-quarter
    const int a  = a0 + al;
    __shared__ float sdec[8][1024];
    for (int i = threadIdx.x; i < 8192; i += 256)
        sdec[i >> 10][i & 1023] = dec[bg * 8192 + i];
    __syncthreads();
    float acc[8];
#pragma unroll
    for (int b = 0; b < 8; ++b) acc[b] = 0.f;
    for (int d = dq * 256; d < dq * 256 + 256; ++d) {
        const float w = Wdec[(size_t)d * 1024 + a];
#pragma unroll
        for (int b = 0; b < 8; ++b) acc[b] += sdec[b][d] * w;
    }
    __shared__ float red[4][8][64];
#pragma unroll
    for (int b = 0; b < 8; ++b) red[dq][b][al] = acc[b];
    __syncthreads();
    if (dq == 0) {
        const float be = benc[a];
#pragma unroll
        for (int b = 0; b < 8; ++b)
            dproj[(bg * 8 + b) * 1024 + a] =
                be + red[0][b][al] + red[1][b][al] + red[2][b][al] + red[3][b][al];
    }
}

// ------------- fused 256^2 energy GEMM (f32 A in-kernel convert) ------------
// A = enc [M,1024] f32 (K-contig), B = WT [N,1024] bf16 (K-contig).
// BM=BN=256, BK=64, 8 waves (2m x 4n), per-wave out 128x64.
// LDS 128 KiB: As/Bs each 2-slot dbuf x 2 halves x [128][64] bf16.
// A-path (T14, reg-staged f32->bf16): per tile t, issue f32 loads for
// A(t+1) half0 at tile start, consume (cvt+ds_write, swizzled dest) after
// qm=0 MFMAs; issue half1 there, consume at tile end. HBM latency hides
// under the MFMA clusters. B-path: global_load_lds, pre-swizzled source.
// Sync per tile: lgkmcnt(0) (ds_writes visible) + vmcnt(0) (B retired; A
// loads already consumed) + ONE s_barrier. Race-free: everything staged in
// tile t is retired before tile t+1 reads it.

#define HT 8192   // elems per half-slot (128 rows * 64 cols)

#define BARRIER()  __builtin_amdgcn_s_barrier()
#define SCHEDB()   __builtin_amdgcn_sched_barrier(0)
#define VMCNT(n)   asm volatile("s_waitcnt vmcnt(" #n ")")
#define LGKM0()    asm volatile("s_waitcnt lgkmcnt(0)")

#define STAGE_B(kt, h) {                                                       \
    const bf16* g_ = WT + (size_t)(n0 + (h)*128 + wave*8 + (lane>>3)) * 1024   \
                     + (kt)*64 + srccol;                                       \
    bf16* l_ = Bs + ((((kt)&1)*2 + (h)) * HT) + wave * 512;                    \
    async_copy16(g_, l_);                                                      \
    async_copy16(g_ + (size_t)64*1024, l_ + 4096);                             \
}

// load A(kt) half h: 4x float4 per thread (rows row0, row0+64 of the half)
#define LOAD_A(kt, h, q0, q1, q2, q3) {                                        \
    const float* g_ = enc + (size_t)(m0 + (h)*128 + row0) * 1024               \
                      + (kt)*64 + cg * 8;                                      \
    q0 = *(const float4*)g_;                                                   \
    q1 = *(const float4*)(g_ + 4);                                             \
    q2 = *(const float4*)(g_ + (size_t)64 * 1024);                             \
    q3 = *(const float4*)(g_ + (size_t)64 * 1024 + 4);                         \
}

// cvt 4x float4 -> 2x bf16x8 and ds_write to slot sl, half h (swizzled dest)
#define WRITE_A(sl, h, q0, q1, q2, q3) {                                       \
    bf16x8 w0_, w1_;                                                           \
    w0_[0]=(bf16)q0.x; w0_[1]=(bf16)q0.y; w0_[2]=(bf16)q0.z; w0_[3]=(bf16)q0.w;\
    w0_[4]=(bf16)q1.x; w0_[5]=(bf16)q1.y; w0_[6]=(bf16)q1.z; w0_[7]=(bf16)q1.w;\
    w1_[0]=(bf16)q2.x; w1_[1]=(bf16)q2.y; w1_[2]=(bf16)q2.z; w1_[3]=(bf16)q2.w;\
    w1_[4]=(bf16)q3.x; w1_[5]=(bf16)q3.y; w1_[6]=(bf16)q3.z; w1_[7]=(bf16)q3.w;\
    bf16* l_ = As + (((sl)*2 + (h)) * HT) + row0 * 64 + wslot * 8;             \
    *(bf16x8*)(l_) = w0_;                                                      \
    *(bf16x8*)(l_ + 4096) = w1_;   /* row0+64 */                               \
}

__global__ __launch_bounds__(512, 2) void energy_gemm_fused(
        const float* __restrict__ enc, const bf16* __restrict__ WT,
        const float* __restrict__ dproj, const float* __restrict__ v,
        float* __restrict__ part) {
    __shared__ __align__(16) bf16 As[4 * HT];   // 64 KiB (2-slot A dbuf)
    __shared__ __align__(16) bf16 Bs[4 * HT];   // 64 KiB (2-slot B dbuf)
    float* esum = (float*)As;                   // aliased: As dead in epilogue

    const int tid  = threadIdx.x;
    const int lane = tid & 63;
    const int wave = tid >> 6;      // 0..7
    const int wm   = wave >> 2;     // 0..1
    const int wn   = wave & 3;      // 0..3
    const int lo   = lane & 15;
    const int hi   = lane >> 4;

    // XCD swizzle: all 4 n-chunks of one m-tile concurrent on ONE XCD
    // (L2-dedups the shared f32 A-panel reads).
    const int L = blockIdx.x;             // 1024 blocks
    const int xcd  = L & 7;
    const int slot = L >> 3;              // 0..127
    const int m_tile  = xcd * 32 + (slot >> 2);
    const int n_chunk = slot & 3;
    const int m0 = m_tile * 256;
    const int n0 = n_chunk * 256;
    const int b  = m0 >> 11;

    // staging lane decomposition
    const int row0  = wave * 8 + (lane >> 3);     // 0..63
    const int cg    = lane & 7;                   // logical col-group
    const int wslot = cg ^ (lane >> 3);           // swizzled phys slot (= cg^(row0&7))
    const int srccol = wslot << 3;                // B pre-swizzled source col
    // ds_read slot XOR (elems)
    const int swz0 = ((hi)     ^ (lo & 7)) << 3;
    const int swz1 = ((4 | hi) ^ (lo & 7)) << 3;

    floatx4 acc[2][2][4][2];
#pragma unroll
    for (int a_ = 0; a_ < 2; ++a_)
#pragma unroll
      for (int b_ = 0; b_ < 2; ++b_)
#pragma unroll
        for (int c_ = 0; c_ < 4; ++c_)
#pragma unroll
          for (int d_ = 0; d_ < 2; ++d_)
            acc[a_][b_][c_][d_] = (floatx4){0.f, 0.f, 0.f, 0.f};

    // hoisted epilogue operands
    float vv[2][2], dp[2][2];
#pragma unroll
    for (int qn = 0; qn < 2; ++qn)
#pragma unroll
      for (int nf = 0; nf < 2; ++nf) {
        int col = n0 + qn * 128 + wn * 32 + nf * 16 + lo;
        vv[qn][nf] = v[col];
        dp[qn][nf] = dproj[b * 1024 + col];
      }

    // prologue: A(0) via regs, B(0) via global_load_lds; full drain once.
    {
        float4 p0, p1, p2, p3, r0, r1, r2, r3;
        LOAD_A(0, 0, p0, p1, p2, p3);
        LOAD_A(0, 1, r0, r1, r2, r3);
        STAGE_B(0, 0); STAGE_B(0, 1);
        WRITE_A(0, 0, p0, p1, p2, p3);
        WRITE_A(0, 1, r0, r1, r2, r3);
    }
    SCHEDB();
    LGKM0();
    VMCNT(0);
    SCHEDB();
    BARRIER();

#pragma unroll 1
    for (int t = 0; t < 16; ++t) {
        const int cur = t & 1, nxt = cur ^ 1;
        const bf16* Ah0 = As + (cur * 2 + 0) * HT;
        const bf16* Ah1 = As + (cur * 2 + 1) * HT;
        const bf16* Bh0 = Bs + (cur * 2 + 0) * HT;
        const bf16* Bh1 = Bs + (cur * 2 + 1) * HT;

        // issue A(t+1) half0 f32 loads (consume after qm=0 MFMAs)
        float4 qa0, qa1, qa2, qa3;
        if (t < 15) { LOAD_A(t + 1, 0, qa0, qa1, qa2, qa3); }

        bf16x8 bfr[2][2][2], af0[4][2], af1[4][2];
#pragma unroll
        for (int qn = 0; qn < 2; ++qn) {
            const bf16* Bh_ = qn ? Bh1 : Bh0;
#pragma unroll
            for (int nf = 0; nf < 2; ++nf) {
                bfr[qn][nf][0] = *(const bf16x8*)(Bh_ + (wn*32 + nf*16 + lo)*64 + swz0);
                bfr[qn][nf][1] = *(const bf16x8*)(Bh_ + (wn*32 + nf*16 + lo)*64 + swz1);
            }
        }
#pragma unroll
        for (int mf = 0; mf < 4; ++mf) {
            af0[mf][0] = *(const bf16x8*)(Ah0 + (wm*64 + mf*16 + lo)*64 + swz0);
            af0[mf][1] = *(const bf16x8*)(Ah0 + (wm*64 + mf*16 + lo)*64 + swz1);
        }
        if (t < 15) { STAGE_B(t + 1, 0); STAGE_B(t + 1, 1); }

        __builtin_amdgcn_s_setprio(1);
#pragma unroll
        for (int kk = 0; kk < 2; ++kk)
#pragma unroll
          for (int mf = 0; mf < 4; ++mf)
#pragma unroll
            for (int qn = 0; qn < 2; ++qn)
#pragma unroll
              for (int nf = 0; nf < 2; ++nf)
                acc[0][qn][mf][nf] = __builtin_amdgcn_mfma_f32_16x16x32_bf16(
                    af0[mf][kk], bfr[qn][nf][kk], acc[0][qn][mf][nf], 0, 0, 0);
        __builtin_amdgcn_s_setprio(0);

        // consume A(t+1) h0; issue h1 (consume at tile end)
        float4 qb0, qb1, qb2, qb3;
        if (t < 15) {
            WRITE_A(nxt, 0, qa0, qa1, qa2, qa3);
            LOAD_A(t + 1, 1, qb0, qb1, qb2, qb3);
        }

#pragma unroll
        for (int mf = 0; mf < 4; ++mf) {
            af1[mf][0] = *(const bf16x8*)(Ah1 + (wm*64 + mf*16 + lo)*64 + swz0);
            af1[mf][1] = *(const bf16x8*)(Ah1 + (wm*64 + mf*16 + lo)*64 + swz1);
        }

        __builtin_amdgcn_s_setprio(1);
#pragma unroll
        for (int kk = 0; kk < 2; ++kk)
#pragma unroll
          for (int mf = 0; mf < 4; ++mf)
#pragma unroll
            for (int qn = 0; qn < 2; ++qn)
#pragma unroll
              for (int nf = 0; nf < 2; ++nf)
                acc[1][qn][mf][nf] = __builtin_amdgcn_mfma_f32_16x16x32_bf16(
                    af1[mf][kk], bfr[qn][nf][kk], acc[1][qn][mf][nf], 0, 0, 0);
        __builtin_amdgcn_s_setprio(0);

        if (t < 15) { WRITE_A(nxt, 1, qb0, qb1, qb2, qb3); }

        SCHEDB();
        LGKM0();      // ds_writes visible to all waves before barrier
        VMCNT(0);     // B(t+1) retired (L2-hot, short); A loads already consumed
        SCHEDB();
        BARRIER();
    }

    // ---- fused epilogue: e[row] = sum_col v[col]*tanh(acc + dproj) ---------
    __syncthreads();   // all LDS reads done; As reusable as esum
#pragma unroll
    for (int qm = 0; qm < 2; ++qm)
#pragma unroll
      for (int mf = 0; mf < 4; ++mf)
#pragma unroll
        for (int r = 0; r < 4; ++r) {
          float s = 0.f;
#pragma unroll
          for (int qn = 0; qn < 2; ++qn)
#pragma unroll
            for (int nf = 0; nf < 2; ++nf)
              s += vv[qn][nf] * fast_tanh(acc[qm][qn][mf][nf][r] + dp[qn][nf]);
          s += __shfl_xor(s, 1);
          s += __shfl_xor(s, 2);
          s += __shfl_xor(s, 4);
          s += __shfl_xor(s, 8);
          if (lo == 0)
            esum[wn * 256 + qm * 128 + wm * 64 + mf * 16 + hi * 4 + r] = s;
        }
    __syncthreads();
    if (tid < 256)
        part[(size_t)n_chunk * M_DIM + m0 + tid] =
            esum[tid] + esum[256 + tid] + esum[512 + tid] + esum[768 + tid];
}

// ------------- fallback f32-staged GEMM (small ws, 8 n-chunks) --------------
__global__ __launch_bounds__(256) void energy_gemm_f32(
        const float* __restrict__ enc, const bf16* __restrict__ WT,
        const float* __restrict__ dproj, const float* __restrict__ v,
        float* __restrict__ part) {
    __shared__ __align__(16) bf16 As[128 * 32];
    __shared__ __align__(16) bf16 Bs[128 * 32];
    __shared__ float esum[128];

    const int tid  = threadIdx.x;
    const int lane = tid & 63;
    const int wave = tid >> 6;
    const int wy = wave >> 1, wx = wave & 1;
    const int L = blockIdx.x;
    const int xcd  = L & 7;
    const int slot = L >> 3;
    const int m_tile = xcd * 64 + (slot >> 3);
    const int n_chunk = slot & 7;
    const int m0 = m_tile * 128;
    const int n0 = n_chunk * 128;
    const int b  = m0 >> 11;

    if (tid < 128) esum[tid] = 0.f;

    floatx4 acc[4][4];
#pragma unroll
    for (int i = 0; i < 4; ++i)
#pragma unroll
        for (int j = 0; j < 4; ++j) acc[i][j] = (floatx4){0.f, 0.f, 0.f, 0.f};

    const int sr = tid >> 2;
    const int sc = (tid & 3) * 8;
    const float* gA = enc + (size_t)(m0 + sr) * 1024 + sc;
    const bf16*  gB = WT  + (size_t)(n0 + sr) * 1024 + sc;
    bf16* lA = As + sr * 32 + sc;
    bf16* lB = Bs + sr * 32 + sc;

    for (int k0 = 0; k0 < K_DIM; k0 += 32) {
        __syncthreads();
#pragma unroll
        for (int rep = 0; rep < 2; ++rep) {
            const float4* p = (const float4*)(gA + (size_t)rep * 64 * 1024 + k0);
            float4 f0 = p[0], f1 = p[1];
            bf16x8 w;
            w[0] = (bf16)f0.x; w[1] = (bf16)f0.y; w[2] = (bf16)f0.z; w[3] = (bf16)f0.w;
            w[4] = (bf16)f1.x; w[5] = (bf16)f1.y; w[6] = (bf16)f1.z; w[7] = (bf16)f1.w;
            *(bf16x8*)(lA + rep * 64 * 32) = w;
            *(bf16x8*)(lB + rep * 64 * 32) =
                *(const bf16x8*)(gB + (size_t)rep * 64 * 1024 + k0);
        }
        __syncthreads();

        bf16x8 af[4], bfrg[4];
#pragma unroll
        for (int i = 0; i < 4; ++i)
            af[i] = *(const bf16x8*)(As + (wy * 64 + i * 16 + (lane & 15)) * 32 + (lane >> 4) * 8);
#pragma unroll
        for (int i = 0; i < 4; ++i)
            bfrg[i] = *(const bf16x8*)(Bs + (wx * 64 + i * 16 + (lane & 15)) * 32 + (lane >> 4) * 8);
#pragma unroll
        for (int mi = 0; mi < 4; ++mi)
#pragma unroll
            for (int ni = 0; ni < 4; ++ni)
                acc[mi][ni] = __builtin_amdgcn_mfma_f32_16x16x32_bf16(
                    af[mi], bfrg[ni], acc[mi][ni], 0, 0, 0);
    }
    __syncthreads();

    float vv[4], dp[4];
#pragma unroll
    for (int ni = 0; ni < 4; ++ni) {
        int col = n0 + wx * 64 + ni * 16 + (lane & 15);
        vv[ni] = v[col];
        dp[ni] = dproj[b * 1024 + col];
    }
#pragma unroll
    for (int mi = 0; mi < 4; ++mi) {
#pragma unroll
        for (int r = 0; r < 4; ++r) {
            float s = 0.f;
#pragma unroll
            for (int ni = 0; ni < 4; ++ni)
                s += vv[ni] * fast_tanh(acc[mi][ni][r] + dp[ni]);
            s += __shfl_xor(s, 1);
            s += __shfl_xor(s, 2);
            s += __shfl_xor(s, 4);
            s += __shfl_xor(s, 8);
            if ((lane & 15) == 0) {
                int row = wy * 64 + mi * 16 + (lane >> 4) * 4 + r;
                atomicAdd(&esum[row], s);
            }
        }
    }
    __syncthreads();
    if (tid < 128) part[(size_t)n_chunk * M_DIM + m0 + tid] = esum[tid];
}

// ------------- masked softmax over T (multiplicative 0/1 mask) --------------
__global__ __launch_bounds__(256) void softmax_kernel(
        const float* __restrict__ part, const int* __restrict__ xlens,
        float* __restrict__ att, int nc) {
    const int b = blockIdx.x, tid = threadIdx.x;
    const int len = xlens[b];
    float e[8];
    float mx = -3.4e38f;
#pragma unroll
    for (int i = 0; i < 8; ++i) {
        const int t = tid + i * 256;
        float s = 0.f;
#pragma unroll 4
        for (int c = 0; c < nc; ++c) s += part[(size_t)c * M_DIM + b * 2048 + t];
        e[i] = (t < len) ? s : 0.f;
        mx = fmaxf(mx, e[i]);
    }
#pragma unroll
    for (int off = 1; off < 64; off <<= 1) mx = fmaxf(mx, __shfl_xor(mx, off));
    __shared__ float sr1[4], sr2[4];
    if ((tid & 63) == 0) sr1[tid >> 6] = mx;
    __syncthreads();
    mx = fmaxf(fmaxf(sr1[0], sr1[1]), fmaxf(sr1[2], sr1[3]));
    float sum = 0.f;
#pragma unroll
    for (int i = 0; i < 8; ++i) { e[i] = __expf(e[i] - mx); sum += e[i]; }
#pragma unroll
    for (int off = 1; off < 64; off <<= 1) sum += __shfl_xor(sum, off);
    if ((tid & 63) == 0) sr2[tid >> 6] = sum;
    __syncthreads();
    sum = sr2[0] + sr2[1] + sr2[2] + sr2[3];
    const float inv = 1.f / sum;
#pragma unroll
    for (int i = 0; i < 8; ++i)
        att[b * 2048 + tid + i * 256] = e[i] * inv;
}

// ------------- context partials: atomic-free, f32 enc -----------------------
__global__ __launch_bounds__(256) void context_part_f32(
        const float* __restrict__ enc, const float* __restrict__ att,
        float* __restrict__ ctxpart) {
    const int b = blockIdx.x, chunk = blockIdx.y, tid = threadIdx.x;
    const int t0 = chunk * 128;
    __shared__ float satt[128];
    if (tid < 128) satt[tid] = att[b * 2048 + t0 + tid];
    __syncthreads();
    const float* base = enc + ((size_t)b * 2048 + t0) * 1024 + tid * 4;
    float a0 = 0.f, a1 = 0.f, a2 = 0.f, a3 = 0.f;
#pragma unroll 4
    for (int t = 0; t < 128; ++t) {
        float4 ev = *(const float4*)(base + (size_t)t * 1024);
        float w = satt[t];
        a0 += w * ev.x; a1 += w * ev.y; a2 += w * ev.z; a3 += w * ev.w;
    }
    float* o = ctxpart + ((size_t)b * 16 + chunk) * 1024 + tid * 4;
    o[0] = a0; o[1] = a1; o[2] = a2; o[3] = a3;
}

__global__ __launch_bounds__(256) void context_reduce_kernel(
        const float* __restrict__ ctxpart, float* __restrict__ out_ctx) {
    const int i = blockIdx.x * 256 + threadIdx.x;     // 0..32767
    const int b = i >> 10, e = i & 1023;
    const float* p = ctxpart + (size_t)b * 16 * 1024 + e;
    float s = 0.f;
#pragma unroll
    for (int c = 0; c < 16; ++c) s += p[c * 1024];
    out_ctx[i] = s;
}

// ------------- fallback context (f32 enc + atomics) -------------------------
__global__ __launch_bounds__(256) void context_kernel_f32(
        const float* __restrict__ enc, const float* __restrict__ att,
        float* __restrict__ ctx) {
    const int b = blockIdx.x, t0 = blockIdx.y * 128, tid = threadIdx.x;
    __shared__ float satt[128];
    if (tid < 128) satt[tid] = att[b * 2048 + t0 + tid];
    __syncthreads();
    const float* base = enc + ((size_t)b * 2048 + t0) * 1024 + tid * 4;
    float a0 = 0.f, a1 = 0.f, a2 = 0.f, a3 = 0.f;
    for (int t = 0; t < 128; ++t) {
        float4 ev = *(const float4*)(base + (size_t)t * 1024);
        float w = satt[t];
        a0 += w * ev.x; a1 += w * ev.y; a2 += w * ev.z; a3 += w * ev.w;
    }
    float* o = ctx + b * 1024 + tid * 4;
    atomicAdd(o + 0, a0); atomicAdd(o + 1, a1);
    atomicAdd(o + 2, a2); atomicAdd(o + 3, a3);
}

extern "C" void kernel_launch(void* const* d_in, const int* in_sizes, int n_in,
                              void* d_out, int out_size, void* d_ws, size_t ws_size,
                              hipStream_t stream) {
    const float* enc   = (const float*)d_in[0];
    const int*   xlens = (const int*)d_in[1];
    const float* dec   = (const float*)d_in[2];
    const float* Wenc  = (const float*)d_in[4];
    const float* benc  = (const float*)d_in[5];
    const float* Wdec  = (const float*)d_in[6];
    const float* v     = (const float*)d_in[7];

    float* out_ctx = (float*)d_out;
    float* out_att = out_ctx + B_DIM * K_DIM;

    char* ws = (char*)d_ws;
    float* dproj   = (float*)ws;                                  // 128 KB
    bf16*  WT      = (bf16*)(ws + (128u << 10));                  // 2 MB
    float* part    = (float*)(ws + (128u << 10) + (2u << 20));    // 2 MB
    float* ctxpart = (float*)(ws + (128u << 10) + (4u << 20));    // 2 MB
    const size_t need = (128u << 10) + (6u << 20);

    transpose_wenc<<<dim3(16, 16), 256, 0, stream>>>(Wenc, WT);
    decproj_kernel<<<dim3(4, 16), 256, 0, stream>>>(dec, Wdec, benc, dproj);

    if (ws_size >= need) {
        energy_gemm_fused<<<1024, 512, 0, stream>>>(enc, WT, dproj, v, part);
        softmax_kernel<<<B_DIM, 256, 0, stream>>>(part, xlens, out_att, 4);
        context_part_f32<<<dim3(B_DIM, 16), 256, 0, stream>>>(enc, out_att, ctxpart);
        context_reduce_kernel<<<B_DIM * K_DIM / 256, 256, 0, stream>>>(ctxpart, out_ctx);
    } else {
        hipMemsetAsync(out_ctx, 0, B_DIM * K_DIM * sizeof(float), stream);
        energy_gemm_f32<<<4096, 256, 0, stream>>>(enc, WT, dproj, v, part);
        softmax_kernel<<<B_DIM, 256, 0, stream>>>(part, xlens, out_att, 8);
        context_kernel_f32<<<dim3(B_DIM, 16), 256, 0, stream>>>(enc, out_att, out_ctx);
    }
}

// Round 9
// 562.673 us; speedup vs baseline: 1.0818x; 1.0818x over previous
//
#include <hip/hip_runtime.h>
#include <hip/hip_bf16.h>
#include <stdint.h>

// B=32, T=2048, E=D=A=1024. f32 I/O; x_lens int32.
// Output = [context (32*1024) ; att (32*2048)] f32.
// Pipeline (3 dispatches + memset):
//   prep  = transpose_wenc || decproj || cvt_enc   (blockIdx range-split)
//   gemm  = R6-core 256^2 bf16-MFMA energy GEMM (3-deep A ring, 1 barrier +
//           counted vmcnt per K-tile, T2 swizzle, T5 setprio, fused v.tanh)
//   sctx  = fused softmax + bf16 context (per-block redundant row stats,
//           deterministic; atomicAdd into zeroed ctx)

typedef __bf16 bf16;
typedef __bf16 bf16x8 __attribute__((ext_vector_type(8)));
typedef __bf16 bf16x4 __attribute__((ext_vector_type(4)));
typedef float floatx4 __attribute__((ext_vector_type(4)));

#define T_DIM 2048
#define B_DIM 32
#define K_DIM 1024   // E
#define N_DIM 1024   // A
#define M_DIM (B_DIM * T_DIM)               // 65536
#define ENC_ELEMS ((size_t)M_DIM * K_DIM)   // 64M

__device__ __forceinline__ void async_copy16(const bf16* g, bf16* l) {
    __builtin_amdgcn_global_load_lds(
        (const __attribute__((address_space(1))) void*)g,
        (__attribute__((address_space(3))) void*)l, 16, 0, 0);
}

__device__ __forceinline__ float fast_tanh(float x) {
    float ax = fabsf(x);
    float e  = __expf(ax + ax);
    float t  = 1.f - 2.f / (e + 1.f);
    return copysignf(t, x);
}

// ------------- prep: transpose_wenc || decproj || cvt_enc -------------------
// grid 2368 x 256: [0,256) transpose, [256,320) decproj, [320,2368) cvt.
__global__ __launch_bounds__(256) void prep_kernel(
        const float* __restrict__ W, bf16* __restrict__ WT,
        const float* __restrict__ dec, const float* __restrict__ Wdec,
        const float* __restrict__ benc, float* __restrict__ dproj,
        const float* __restrict__ enc, bf16* __restrict__ encb) {
    __shared__ union {
        bf16 tile[64][65];                                   // 8.3 KB
        struct { float sdec[8][1024]; float red[4][8][64]; } dp;  // 40 KB
    } sm;
    const int bid = blockIdx.x;
    const int tid = threadIdx.x;

    if (bid < 256) {
        // ---- W_enc f32 [E,A] -> W_encT bf16 [A,E] ----
        const int e0 = (bid & 15) * 64, a0 = (bid >> 4) * 64;
        const int c = tid & 63, r0 = tid >> 6;
#pragma unroll
        for (int p = 0; p < 16; ++p) {
            int r = p * 4 + r0;
            sm.tile[r][c] = (bf16)W[(size_t)(e0 + r) * 1024 + a0 + c];
        }
        __syncthreads();
#pragma unroll
        for (int p = 0; p < 16; ++p) {
            int r = p * 4 + r0;
            WT[(size_t)(a0 + r) * 1024 + e0 + c] = sm.tile[c][r];
        }
    } else if (bid < 320) {
        // ---- dec_proj[b,a] = b_enc[a] + sum_d dec[b,d] W_dec[d,a] ----
        const int bg = (bid - 256) >> 4;      // batch group of 8
        const int a0 = ((bid - 256) & 15) * 64;
        const int al = tid & 63;
        const int dq = tid >> 6;              // d-quarter
        const int a  = a0 + al;
        for (int i = tid; i < 8192; i += 256)
            sm.dp.sdec[i >> 10][i & 1023] = dec[bg * 8192 + i];
        __syncthreads();
        float acc[8];
#pragma unroll
        for (int b = 0; b < 8; ++b) acc[b] = 0.f;
        for (int d = dq * 256; d < dq * 256 + 256; ++d) {
            const float w = Wdec[(size_t)d * 1024 + a];
#pragma unroll
            for (int b = 0; b < 8; ++b) acc[b] += sm.dp.sdec[b][d] * w;
        }
        __syncthreads();
#pragma unroll
        for (int b = 0; b < 8; ++b) sm.dp.red[dq][b][al] = acc[b];
        __syncthreads();
        if (dq == 0) {
            const float be = benc[a];
#pragma unroll
            for (int b = 0; b < 8; ++b)
                dproj[(bg * 8 + b) * 1024 + a] =
                    be + sm.dp.red[0][b][al] + sm.dp.red[1][b][al] +
                         sm.dp.red[2][b][al] + sm.dp.red[3][b][al];
        }
    } else {
        // ---- enc f32 -> bf16 (contiguous, grid-stride over 2048 blocks) ----
        size_t i = ((size_t)(bid - 320) * 256 + tid) * 8;
        const size_t stride = (size_t)2048 * 256 * 8;
        for (; i < ENC_ELEMS; i += stride) {
            float4 f0 = *(const float4*)(enc + i);
            float4 f1 = *(const float4*)(enc + i + 4);
            bf16x8 w;
            w[0] = (bf16)f0.x; w[1] = (bf16)f0.y; w[2] = (bf16)f0.z; w[3] = (bf16)f0.w;
            w[4] = (bf16)f1.x; w[5] = (bf16)f1.y; w[6] = (bf16)f1.z; w[7] = (bf16)f1.w;
            *(bf16x8*)(encb + i) = w;
        }
    }
}

// ------------- 256^2 energy GEMM, 1 barrier per K-tile (R6 core) ------------
// A = encb [M,1024] bf16 (K-contig), B = WT [N,1024] bf16 (K-contig).
// BM=BN=256, BK=64, 8 waves (2m x 4n), per-wave out 128x64.
// LDS 160 KiB: As = 3-tile ring (96K), Bs = 2-tile dbuf (64K); esum aliased.
// Per tile t: {read bfr+af0; stage B(t+1); 32 MFMA qm=0}
//             {read af1; stage A(t+2); 32 MFMA qm=1}  vmcnt(4); s_barrier.
// Hazard audit: at end-of-tile vmcnt(4), outstanding = 4 carried A(t+1) +
// 4 B(t+1) + 4 A(t+2); wait-to-4 retires A(t+1) and B(t+1) (both read at
// t+1), leaves only A(t+2) (read at t+2, after next tile's barrier).

#define HT 8192   // elems per half-slot (128 rows * 64 cols)

#define BARRIER()  __builtin_amdgcn_s_barrier()
#define SCHEDB()   __builtin_amdgcn_sched_barrier(0)
#define VMCNT(n)   asm volatile("s_waitcnt vmcnt(" #n ")")

#define STAGE_A(kt, h, sl) {                                                   \
    const bf16* g_ = encb + (size_t)(m0 + (h)*128 + wave*8 + (lane>>3)) * 1024 \
                     + (kt)*64 + srccol;                                       \
    bf16* l_ = As + (((sl)*2 + (h)) * HT) + wave * 512;                        \
    async_copy16(g_, l_);                                                      \
    async_copy16(g_ + (size_t)64*1024, l_ + 4096);                             \
}
#define STAGE_B(kt, h) {                                                       \
    const bf16* g_ = WT + (size_t)(n0 + (h)*128 + wave*8 + (lane>>3)) * 1024   \
                     + (kt)*64 + srccol;                                       \
    bf16* l_ = Bs + ((((kt)&1)*2 + (h)) * HT) + wave * 512;                    \
    async_copy16(g_, l_);                                                      \
    async_copy16(g_ + (size_t)64*1024, l_ + 4096);                             \
}

__global__ __launch_bounds__(512, 2) void energy_gemm_8ph(
        const bf16* __restrict__ encb, const bf16* __restrict__ WT,
        const float* __restrict__ dproj, const float* __restrict__ v,
        float* __restrict__ part) {
    __shared__ __align__(16) bf16 As[6 * HT];   // 96 KiB (3-tile A ring)
    __shared__ __align__(16) bf16 Bs[4 * HT];   // 64 KiB (2-tile B dbuf)
    float* esum = (float*)As;                   // aliased: As dead in epilogue

    const int tid  = threadIdx.x;
    const int lane = tid & 63;
    const int wave = tid >> 6;      // 0..7
    const int wm   = wave >> 2;     // 0..1
    const int wn   = wave & 3;      // 0..3
    const int lo   = lane & 15;
    const int hi   = lane >> 4;

    // XCD swizzle: all 4 n-chunks of one m-tile consecutive on ONE XCD.
    const int L = blockIdx.x;             // 1024 blocks
    const int xcd  = L & 7;
    const int slot = L >> 3;              // 0..127
    const int m_tile  = xcd * 32 + (slot >> 2);
    const int n_chunk = slot & 3;
    const int m0 = m_tile * 256;
    const int n0 = n_chunk * 256;
    const int b  = m0 >> 11;

    // per-lane pre-swizzled source col-group (elems) for staging
    const int srccol = (((lane & 7) ^ (lane >> 3)) << 3);
    // ds_read slot XOR (elems)
    const int swz0 = ((hi)     ^ (lo & 7)) << 3;
    const int swz1 = ((4 | hi) ^ (lo & 7)) << 3;

    floatx4 acc[2][2][4][2];
#pragma unroll
    for (int a_ = 0; a_ < 2; ++a_)
#pragma unroll
      for (int b_ = 0; b_ < 2; ++b_)
#pragma unroll
        for (int c_ = 0; c_ < 4; ++c_)
#pragma unroll
          for (int d_ = 0; d_ < 2; ++d_)
            acc[a_][b_][c_][d_] = (floatx4){0.f, 0.f, 0.f, 0.f};

    // hoisted epilogue operands (loaded before the counted-vmcnt region)
    float vv[2][2], dp[2][2];
#pragma unroll
    for (int qn = 0; qn < 2; ++qn)
#pragma unroll
      for (int nf = 0; nf < 2; ++nf) {
        int col = n0 + qn * 128 + wn * 32 + nf * 16 + lo;
        vv[qn][nf] = v[col];
        dp[qn][nf] = dproj[b * 1024 + col];
      }
    SCHEDB();
    VMCNT(0);   // zero the vmcnt baseline so counted waits are exact
    SCHEDB();

    // prologue: B(0), A(0) slot0, A(1) slot1. vmcnt(4) retires B(0)+A(0).
    STAGE_B(0, 0); STAGE_B(0, 1);
    STAGE_A(0, 0, 0); STAGE_A(0, 1, 0);
    STAGE_A(1, 0, 1); STAGE_A(1, 1, 1);
    SCHEDB();
    VMCNT(4);
    SCHEDB();
    BARRIER();

    int aslot = 0;
#pragma unroll 1
    for (int t = 0; t < 16; ++t) {
        const int tb   = t & 1;
        const int asl2 = (aslot >= 1) ? (aslot - 1) : 2;   // (t+2)%3
        const bf16* Bh0 = Bs + (tb * 2 + 0) * HT;
        const bf16* Bh1 = Bs + (tb * 2 + 1) * HT;
        const bf16* Ah0 = As + (aslot * 2 + 0) * HT;
        const bf16* Ah1 = As + (aslot * 2 + 1) * HT;

        bf16x8 bfr[2][2][2], af0[4][2], af1[4][2];
        // B fragments for BOTH qm halves (deduped: read once per tile)
#pragma unroll
        for (int qn = 0; qn < 2; ++qn) {
            const bf16* Bh_ = qn ? Bh1 : Bh0;
#pragma unroll
            for (int nf = 0; nf < 2; ++nf) {
                bfr[qn][nf][0] = *(const bf16x8*)(Bh_ + (wn*32 + nf*16 + lo)*64 + swz0);
                bfr[qn][nf][1] = *(const bf16x8*)(Bh_ + (wn*32 + nf*16 + lo)*64 + swz1);
            }
        }
#pragma unroll
        for (int mf = 0; mf < 4; ++mf) {
            af0[mf][0] = *(const bf16x8*)(Ah0 + (wm*64 + mf*16 + lo)*64 + swz0);
            af0[mf][1] = *(const bf16x8*)(Ah0 + (wm*64 + mf*16 + lo)*64 + swz1);
        }
        if (t < 15) { STAGE_B(t + 1, 0); STAGE_B(t + 1, 1); }

        __builtin_amdgcn_s_setprio(1);
#pragma unroll
        for (int kk = 0; kk < 2; ++kk)
#pragma unroll
          for (int mf = 0; mf < 4; ++mf)
#pragma unroll
            for (int qn = 0; qn < 2; ++qn)
#pragma unroll
              for (int nf = 0; nf < 2; ++nf)
                acc[0][qn][mf][nf] = __builtin_amdgcn_mfma_f32_16x16x32_bf16(
                    af0[mf][kk], bfr[qn][nf][kk], acc[0][qn][mf][nf], 0, 0, 0);
        __builtin_amdgcn_s_setprio(0);

#pragma unroll
        for (int mf = 0; mf < 4; ++mf) {
            af1[mf][0] = *(const bf16x8*)(Ah1 + (wm*64 + mf*16 + lo)*64 + swz0);
            af1[mf][1] = *(const bf16x8*)(Ah1 + (wm*64 + mf*16 + lo)*64 + swz1);
        }
        if (t < 14) { STAGE_A(t + 2, 0, asl2); STAGE_A(t + 2, 1, asl2); }

        __builtin_amdgcn_s_setprio(1);
#pragma unroll
        for (int kk = 0; kk < 2; ++kk)
#pragma unroll
          for (int mf = 0; mf < 4; ++mf)
#pragma unroll
            for (int qn = 0; qn < 2; ++qn)
#pragma unroll
              for (int nf = 0; nf < 2; ++nf)
                acc[1][qn][mf][nf] = __builtin_amdgcn_mfma_f32_16x16x32_bf16(
                    af1[mf][kk], bfr[qn][nf][kk], acc[1][qn][mf][nf], 0, 0, 0);
        __builtin_amdgcn_s_setprio(0);

        SCHEDB();
        if (t < 14) { VMCNT(4); } else if (t == 14) { VMCNT(0); }
        SCHEDB();
        BARRIER();
        aslot = (aslot == 2) ? 0 : aslot + 1;
    }

    // ---- fused epilogue: e[row] = sum_col v[col]*tanh(acc + dproj) ---------
    __syncthreads();   // all LDS reads done; As reusable as esum
#pragma unroll
    for (int qm = 0; qm < 2; ++qm)
#pragma unroll
      for (int mf = 0; mf < 4; ++mf)
#pragma unroll
        for (int r = 0; r < 4; ++r) {
          float s = 0.f;
#pragma unroll
          for (int qn = 0; qn < 2; ++qn)
#pragma unroll
            for (int nf = 0; nf < 2; ++nf)
              s += vv[qn][nf] * fast_tanh(acc[qm][qn][mf][nf][r] + dp[qn][nf]);
          s += __shfl_xor(s, 1);
          s += __shfl_xor(s, 2);
          s += __shfl_xor(s, 4);
          s += __shfl_xor(s, 8);
          if (lo == 0)
            esum[wn * 256 + qm * 128 + wm * 64 + mf * 16 + hi * 4 + r] = s;
        }
    __syncthreads();
    if (tid < 256)
        part[(size_t)n_chunk * M_DIM + m0 + tid] =
            esum[tid] + esum[256 + tid] + esum[512 + tid] + esum[768 + tid];
}

// ------------- fused softmax + context (bf16 enc, atomic ctx) ---------------
// grid (32 b, 16 chunks) x 256. Each block redundantly computes the row's
// max/sum from part (L2-hot, deterministic & identical across blocks), writes
// its att chunk, then accumulates its 128-t context partial via atomicAdd
// into zeroed ctx. Replaces softmax + context_part + context_reduce.
__global__ __launch_bounds__(256) void softmax_context(
        const float* __restrict__ part, const int* __restrict__ xlens,
        const bf16* __restrict__ encb, float* __restrict__ att,
        float* __restrict__ ctx) {
    const int b = blockIdx.x, chunk = blockIdx.y, tid = threadIdx.x;
    const int t0 = chunk * 128;
    const int len = xlens[b];
    __shared__ float se[2048];
    __shared__ float sr1[4], sr2[4];
    __shared__ float satt[128];

    float e[8];
    float mx = -3.4e38f;
#pragma unroll
    for (int i = 0; i < 8; ++i) {
        const int t = tid + i * 256;
        float s = 0.f;
#pragma unroll
        for (int c = 0; c < 4; ++c) s += part[(size_t)c * M_DIM + b * 2048 + t];
        e[i] = (t < len) ? s : 0.f;
        se[t] = e[i];
        mx = fmaxf(mx, e[i]);
    }
#pragma unroll
    for (int off = 1; off < 64; off <<= 1) mx = fmaxf(mx, __shfl_xor(mx, off));
    if ((tid & 63) == 0) sr1[tid >> 6] = mx;
    __syncthreads();
    mx = fmaxf(fmaxf(sr1[0], sr1[1]), fmaxf(sr1[2], sr1[3]));
    float sum = 0.f;
#pragma unroll
    for (int i = 0; i < 8; ++i) sum += __expf(e[i] - mx);
#pragma unroll
    for (int off = 1; off < 64; off <<= 1) sum += __shfl_xor(sum, off);
    if ((tid & 63) == 0) sr2[tid >> 6] = sum;
    __syncthreads();
    sum = sr2[0] + sr2[1] + sr2[2] + sr2[3];
    const float inv = 1.f / sum;

    if (tid < 128) {
        float a = __expf(se[t0 + tid] - mx) * inv;
        satt[tid] = a;
        att[b * 2048 + t0 + tid] = a;
    }
    __syncthreads();

    const bf16* base = encb + ((size_t)b * 2048 + t0) * 1024 + tid * 4;
    float a0 = 0.f, a1 = 0.f, a2 = 0.f, a3 = 0.f;
#pragma unroll 4
    for (int t = 0; t < 128; ++t) {
        bf16x4 ev = *(const bf16x4*)(base + (size_t)t * 1024);
        float w = satt[t];
        a0 += w * (float)ev[0]; a1 += w * (float)ev[1];
        a2 += w * (float)ev[2]; a3 += w * (float)ev[3];
    }
    float* o = ctx + b * 1024 + tid * 4;
    atomicAdd(o + 0, a0); atomicAdd(o + 1, a1);
    atomicAdd(o + 2, a2); atomicAdd(o + 3, a3);
}

// ------------- fallback f32-staged GEMM (small ws, 8 n-chunks) --------------
__global__ __launch_bounds__(256) void energy_gemm_f32(
        const float* __restrict__ enc, const bf16* __restrict__ WT,
        const float* __restrict__ dproj, const float* __restrict__ v,
        float* __restrict__ part) {
    __shared__ __align__(16) bf16 Asf[128 * 32];
    __shared__ __align__(16) bf16 Bsf[128 * 32];
    __shared__ float esum[128];

    const int tid  = threadIdx.x;
    const int lane = tid & 63;
    const int wave = tid >> 6;
    const int wy = wave >> 1, wx = wave & 1;
    const int L = blockIdx.x;
    const int xcd  = L & 7;
    const int slot = L >> 3;
    const int m_tile = xcd * 64 + (slot >> 3);
    const int n_chunk = slot & 7;
    const int m0 = m_tile * 128;
    const int n0 = n_chunk * 128;
    const int b  = m0 >> 11;

    if (tid < 128) esum[tid] = 0.f;

    floatx4 acc[4][4];
#pragma unroll
    for (int i = 0; i < 4; ++i)
#pragma unroll
        for (int j = 0; j < 4; ++j) acc[i][j] = (floatx4){0.f, 0.f, 0.f, 0.f};

    const int sr = tid >> 2;
    const int sc = (tid & 3) * 8;
    const float* gA = enc + (size_t)(m0 + sr) * 1024 + sc;
    const bf16*  gB = WT  + (size_t)(n0 + sr) * 1024 + sc;
    bf16* lA = Asf + sr * 32 + sc;
    bf16* lB = Bsf + sr * 32 + sc;

    for (int k0 = 0; k0 < K_DIM; k0 += 32) {
        __syncthreads();
#pragma unroll
        for (int rep = 0; rep < 2; ++rep) {
            const float4* p = (const float4*)(gA + (size_t)rep * 64 * 1024 + k0);
            float4 f0 = p[0], f1 = p[1];
            bf16x8 w;
            w[0] = (bf16)f0.x; w[1] = (bf16)f0.y; w[2] = (bf16)f0.z; w[3] = (bf16)f0.w;
            w[4] = (bf16)f1.x; w[5] = (bf16)f1.y; w[6] = (bf16)f1.z; w[7] = (bf16)f1.w;
            *(bf16x8*)(lA + rep * 64 * 32) = w;
            *(bf16x8*)(lB + rep * 64 * 32) =
                *(const bf16x8*)(gB + (size_t)rep * 64 * 1024 + k0);
        }
        __syncthreads();

        bf16x8 af[4], bfrg[4];
#pragma unroll
        for (int i = 0; i < 4; ++i)
            af[i] = *(const bf16x8*)(Asf + (wy * 64 + i * 16 + (lane & 15)) * 32 + (lane >> 4) * 8);
#pragma unroll
        for (int i = 0; i < 4; ++i)
            bfrg[i] = *(const bf16x8*)(Bsf + (wx * 64 + i * 16 + (lane & 15)) * 32 + (lane >> 4) * 8);
#pragma unroll
        for (int mi = 0; mi < 4; ++mi)
#pragma unroll
            for (int ni = 0; ni < 4; ++ni)
                acc[mi][ni] = __builtin_amdgcn_mfma_f32_16x16x32_bf16(
                    af[mi], bfrg[ni], acc[mi][ni], 0, 0, 0);
    }
    __syncthreads();

    float vv[4], dp[4];
#pragma unroll
    for (int ni = 0; ni < 4; ++ni) {
        int col = n0 + wx * 64 + ni * 16 + (lane & 15);
        vv[ni] = v[col];
        dp[ni] = dproj[b * 1024 + col];
    }
#pragma unroll
    for (int mi = 0; mi < 4; ++mi) {
#pragma unroll
        for (int r = 0; r < 4; ++r) {
            float s = 0.f;
#pragma unroll
            for (int ni = 0; ni < 4; ++ni)
                s += vv[ni] * fast_tanh(acc[mi][ni][r] + dp[ni]);
            s += __shfl_xor(s, 1);
            s += __shfl_xor(s, 2);
            s += __shfl_xor(s, 4);
            s += __shfl_xor(s, 8);
            if ((lane & 15) == 0) {
                int row = wy * 64 + mi * 16 + (lane >> 4) * 4 + r;
                atomicAdd(&esum[row], s);
            }
        }
    }
    __syncthreads();
    if (tid < 128) part[(size_t)n_chunk * M_DIM + m0 + tid] = esum[tid];
}

// ------------- fallback masked softmax --------------------------------------
__global__ __launch_bounds__(256) void softmax_kernel(
        const float* __restrict__ part, const int* __restrict__ xlens,
        float* __restrict__ att, int nc) {
    const int b = blockIdx.x, tid = threadIdx.x;
    const int len = xlens[b];
    float e[8];
    float mx = -3.4e38f;
#pragma unroll
    for (int i = 0; i < 8; ++i) {
        const int t = tid + i * 256;
        float s = 0.f;
#pragma unroll 4
        for (int c = 0; c < nc; ++c) s += part[(size_t)c * M_DIM + b * 2048 + t];
        e[i] = (t < len) ? s : 0.f;
        mx = fmaxf(mx, e[i]);
    }
#pragma unroll
    for (int off = 1; off < 64; off <<= 1) mx = fmaxf(mx, __shfl_xor(mx, off));
    __shared__ float sr1[4], sr2[4];
    if ((tid & 63) == 0) sr1[tid >> 6] = mx;
    __syncthreads();
    mx = fmaxf(fmaxf(sr1[0], sr1[1]), fmaxf(sr1[2], sr1[3]));
    float sum = 0.f;
#pragma unroll
    for (int i = 0; i < 8; ++i) { e[i] = __expf(e[i] - mx); sum += e[i]; }
#pragma unroll
    for (int off = 1; off < 64; off <<= 1) sum += __shfl_xor(sum, off);
    if ((tid & 63) == 0) sr2[tid >> 6] = sum;
    __syncthreads();
    sum = sr2[0] + sr2[1] + sr2[2] + sr2[3];
    const float inv = 1.f / sum;
#pragma unroll
    for (int i = 0; i < 8; ++i)
        att[b * 2048 + tid + i * 256] = e[i] * inv;
}

// ------------- fallback transpose / decproj / context -----------------------
__global__ __launch_bounds__(256) void transpose_wenc(
        const float* __restrict__ W, bf16* __restrict__ WT) {
    __shared__ bf16 tile[64][65];
    const int e0 = blockIdx.x * 64, a0 = blockIdx.y * 64;
    const int c = threadIdx.x & 63, r0 = threadIdx.x >> 6;
#pragma unroll
    for (int p = 0; p < 16; ++p) {
        int r = p * 4 + r0;
        tile[r][c] = (bf16)W[(size_t)(e0 + r) * 1024 + a0 + c];
    }
    __syncthreads();
#pragma unroll
    for (int p = 0; p < 16; ++p) {
        int r = p * 4 + r0;
        WT[(size_t)(a0 + r) * 1024 + e0 + c] = tile[c][r];
    }
}

__global__ __launch_bounds__(256) void decproj_kernel(
        const float* __restrict__ dec, const float* __restrict__ Wdec,
        const float* __restrict__ benc, float* __restrict__ dproj) {
    const int bg = blockIdx.x;
    const int a0 = blockIdx.y * 64;
    const int al = threadIdx.x & 63;
    const int dq = threadIdx.x >> 6;
    const int a  = a0 + al;
    __shared__ float sdec[8][1024];
    for (int i = threadIdx.x; i < 8192; i += 256)
        sdec[i >> 10][i & 1023] = dec[bg * 8192 + i];
    __syncthreads();
    float acc[8];
#pragma unroll
    for (int b = 0; b < 8; ++b) acc[b] = 0.f;
    for (int d = dq * 256; d < dq * 256 + 256; ++d) {
        const float w = Wdec[(size_t)d * 1024 + a];
#pragma unroll
        for (int b = 0; b < 8; ++b) acc[b] += sdec[b][d] * w;
    }
    __shared__ float red[4][8][64];
#pragma unroll
    for (int b = 0; b < 8; ++b) red[dq][b][al] = acc[b];
    __syncthreads();
    if (dq == 0) {
        const float be = benc[a];
#pragma unroll
        for (int b = 0; b < 8; ++b)
            dproj[(bg * 8 + b) * 1024 + a] =
                be + red[0][b][al] + red[1][b][al] + red[2][b][al] + red[3][b][al];
    }
}

__global__ __launch_bounds__(256) void context_kernel_f32(
        const float* __restrict__ enc, const float* __restrict__ att,
        float* __restrict__ ctx) {
    const int b = blockIdx.x, t0 = blockIdx.y * 128, tid = threadIdx.x;
    __shared__ float satt[128];
    if (tid < 128) satt[tid] = att[b * 2048 + t0 + tid];
    __syncthreads();
    const float* base = enc + ((size_t)b * 2048 + t0) * 1024 + tid * 4;
    float a0 = 0.f, a1 = 0.f, a2 = 0.f, a3 = 0.f;
    for (int t = 0; t < 128; ++t) {
        float4 ev = *(const float4*)(base + (size_t)t * 1024);
        float w = satt[t];
        a0 += w * ev.x; a1 += w * ev.y; a2 += w * ev.z; a3 += w * ev.w;
    }
    float* o = ctx + b * 1024 + tid * 4;
    atomicAdd(o + 0, a0); atomicAdd(o + 1, a1);
    atomicAdd(o + 2, a2); atomicAdd(o + 3, a3);
}

extern "C" void kernel_launch(void* const* d_in, const int* in_sizes, int n_in,
                              void* d_out, int out_size, void* d_ws, size_t ws_size,
                              hipStream_t stream) {
    const float* enc   = (const float*)d_in[0];
    const int*   xlens = (const int*)d_in[1];
    const float* dec   = (const float*)d_in[2];
    const float* Wenc  = (const float*)d_in[4];
    const float* benc  = (const float*)d_in[5];
    const float* Wdec  = (const float*)d_in[6];
    const float* v     = (const float*)d_in[7];

    float* out_ctx = (float*)d_out;
    float* out_att = out_ctx + B_DIM * K_DIM;

    char* ws = (char*)d_ws;
    float* dproj = (float*)ws;                                  // 128 KB
    bf16*  WT    = (bf16*)(ws + (128u << 10));                  // 2 MB
    float* part  = (float*)(ws + (128u << 10) + (2u << 20));    // 2 MB (use 1)
    bf16*  encb  = (bf16*)(ws + (128u << 10) + (4u << 20));     // 128 MB
    const size_t need = (128u << 10) + (4u << 20) + ENC_ELEMS * 2;

    if (ws_size >= need) {
        prep_kernel<<<2368, 256, 0, stream>>>(Wenc, WT, dec, Wdec, benc, dproj,
                                              enc, encb);
        energy_gemm_8ph<<<1024, 512, 0, stream>>>(encb, WT, dproj, v, part);
        hipMemsetAsync(out_ctx, 0, B_DIM * K_DIM * sizeof(float), stream);
        softmax_context<<<dim3(B_DIM, 16), 256, 0, stream>>>(part, xlens, encb,
                                                             out_att, out_ctx);
    } else {
        transpose_wenc<<<dim3(16, 16), 256, 0, stream>>>(Wenc, WT);
        decproj_kernel<<<dim3(4, 16), 256, 0, stream>>>(dec, Wdec, benc, dproj);
        hipMemsetAsync(out_ctx, 0, B_DIM * K_DIM * sizeof(float), stream);
        energy_gemm_f32<<<4096, 256, 0, stream>>>(enc, WT, dproj, v, part);
        softmax_kernel<<<B_DIM, 256, 0, stream>>>(part, xlens, out_att, 8);
        context_kernel_f32<<<dim3(B_DIM, 16), 256, 0, stream>>>(enc, out_att, out_ctx);
    }
}